// Round 9
// baseline (259.189 us; speedup 1.0000x reference)
//
#include <hip/hip_runtime.h>

#define TOKENS 8192
#define IN_F   4096
#define OUT_F  4096

#define BM 256
#define BN 256
#define BK 64
#define NT (IN_F / BK)   // 64 K-tiles

typedef __attribute__((ext_vector_type(4))) float  f32x4;
typedef __attribute__((ext_vector_type(4))) int    i32x4;

typedef const __attribute__((address_space(1))) void gas_void;
typedef __attribute__((address_space(3))) void las_void;

// ---------------------------------------------------------------------------
// quant_x: per-token symmetric i8 quantization. One block (256 thr) per row.
// ---------------------------------------------------------------------------
__global__ __launch_bounds__(256) void quant_x_kernel(const float* __restrict__ x,
                                                      signed char* __restrict__ xq,
                                                      float* __restrict__ dx) {
    const int row  = blockIdx.x;
    const int tid  = threadIdx.x;
    const int lane = tid & 63;
    const int wv   = tid >> 6;
    const float* xr = x + (size_t)row * IN_F;

    float v[16];
#pragma unroll
    for (int k = 0; k < 4; ++k) {
        f32x4 t = *(const f32x4*)(xr + k * 1024 + tid * 4);
#pragma unroll
        for (int j = 0; j < 4; ++j) v[k * 4 + j] = t[j];
    }
    float m = 0.f;
#pragma unroll
    for (int j = 0; j < 16; ++j) m = fmaxf(m, fabsf(v[j]));
#pragma unroll
    for (int off = 32; off >= 1; off >>= 1) m = fmaxf(m, __shfl_xor(m, off));
    __shared__ float sm[4];
    if (lane == 0) sm[wv] = m;
    __syncthreads();
    m = fmaxf(fmaxf(sm[0], sm[1]), fmaxf(sm[2], sm[3]));

    const float inv = 127.0f / m;
    if (tid == 0) dx[row] = m * (1.0f / 127.0f);

    int* out = (int*)(xq + (size_t)row * IN_F);
#pragma unroll
    for (int k = 0; k < 4; ++k) {
        int p = 0;
#pragma unroll
        for (int j = 0; j < 4; ++j) {
            int q = (int)rintf(v[k * 4 + j] * inv);
            p |= (q & 0xff) << (8 * j);
        }
        out[k * 256 + tid] = p;
    }
}

// ---------------------------------------------------------------------------
// quant_w: per-out-row integer re-scale of ternary weights.
// ---------------------------------------------------------------------------
__global__ __launch_bounds__(256) void quant_w_kernel(const int* __restrict__ tern,
                                                      const float* __restrict__ scales,
                                                      signed char* __restrict__ wq,
                                                      float* __restrict__ dw) {
    const int o   = blockIdx.x;
    const int tid = threadIdx.x;
    const float* sr = scales + o * 32;

    float smax = 0.f;
#pragma unroll
    for (int g = 0; g < 32; ++g) smax = fmaxf(smax, sr[g]);
    if (tid == 0) dw[o] = smax * (1.0f / 127.0f);

    const int g  = tid >> 3;
    const int iq = (int)rintf(sr[g] * (127.0f / smax));

    const i32x4* tp = (const i32x4*)(tern + (size_t)o * IN_F + tid * 16);
    i32x4 out;
#pragma unroll
    for (int k = 0; k < 4; ++k) {
        i32x4 t = tp[k];
        int p = 0;
#pragma unroll
        for (int j = 0; j < 4; ++j) p |= ((t[j] * iq) & 0xff) << (8 * j);
        out[k] = p;
    }
    *(i32x4*)(wq + (size_t)o * IN_F + tid * 16) = out;
}

// ---------------------------------------------------------------------------
// C[M][N] = (xq . wq^T) * dx[m] * dw[n],  i8 MFMA 16x16x64, i32 acc.
// 256x256 tile, BK=64, 8 waves (2M x 4N), per-wave 128x64, acc 128 AGPR.
// r9: B (weights) BYPASSES LDS — per-wave B-frags loaded global->reg one
// tile ahead (L2-resident wq; 32 KB/CU/tile = 24 B/cy << L2 56 B/cy/CU),
// double-buffered bA/bB via unroll-2 (static names, rule #20).
// A stays in LDS (4x reuse), triple-buffered 3x16 KB = 48 KiB, swizzled
// row-pair layout (r7/r8-verified conflict-free).
// Body t: ds_reads a[0-7] (buf t%3) | B-loads(t+1)->bNxt | stage A(t+2) |
//         4 QUADs (order (0,0)(0,2)(4,0)(4,2): MFMA starts after 4 reads)
//         | vmcnt(6) gate | barrier.
// vmcnt(6) is order-robust: all 6 VMEM ops issued in body t are newer than
// stage(t+1) => <=6 outstanding implies stage(t+1) drained; sched_barrier(0)
// blocks cross-body VMEM motion. Hazard stage(t+2) vs reads(t-1): reads
// lgkm-complete before consuming MFMA -> before barrier arrival -> ordered.
// ---------------------------------------------------------------------------

#define QUAD(MI0, NI0, BC)                                                     \
  do {                                                                         \
    __builtin_amdgcn_s_setprio(1);                                             \
    _Pragma("unroll") for (int mi = 0; mi < 4; ++mi)                           \
      _Pragma("unroll") for (int ni = 0; ni < 2; ++ni)                         \
          acc[(MI0)+mi][(NI0)+ni] = __builtin_amdgcn_mfma_i32_16x16x64_i8(     \
              a[(MI0)+mi], BC[(NI0)+ni], acc[(MI0)+mi][(NI0)+ni], 0, 0, 0);    \
    __builtin_amdgcn_s_setprio(0);                                             \
  } while (0)

#define BODY(T, BC, BNX)                                                       \
  do {                                                                         \
    const int c_    = (T) % 3;                                                 \
    const int abase = c_ * 16384;                                              \
    _Pragma("unroll") for (int mi = 0; mi < 8; ++mi)                           \
        a[mi] = *(const i32x4*)&As[abase + pA[mi]];                            \
    if ((T) + 1 < NT) {                                                        \
      _Pragma("unroll") for (int ni = 0; ni < 4; ++ni)                         \
          BNX[ni] = *(const i32x4*)(bp[ni] + ((T) + 1) * BK);                  \
    }                                                                          \
    if ((T) + 2 < NT) stage_tile(((T) + 2) % 3, ((T) + 2) * BK);               \
    QUAD(0, 0, BC); QUAD(0, 2, BC); QUAD(4, 0, BC); QUAD(4, 2, BC);            \
    if ((T) + 2 < NT)      asm volatile("s_waitcnt vmcnt(6)" ::: "memory");    \
    else if ((T) + 1 < NT) asm volatile("s_waitcnt vmcnt(4)" ::: "memory");    \
    __builtin_amdgcn_sched_barrier(0);                                         \
    __builtin_amdgcn_s_barrier();                                              \
    __builtin_amdgcn_sched_barrier(0);                                         \
  } while (0)

__global__ __launch_bounds__(512, 2) void gemm_i8_kernel(
        const signed char* __restrict__ A,
        const signed char* __restrict__ B,
        const float* __restrict__ dX,
        const float* __restrict__ dW,
        float* __restrict__ C) {
    __shared__ __align__(16) signed char As[3 * 16384];

    const int tid  = threadIdx.x;
    const int wave = tid >> 6;
    const int lane = tid & 63;
    const int wm   = wave >> 2;        // 0-1
    const int wn   = wave & 3;         // 0-3
    const int lg   = lane >> 4;        // 0-3
    const int lr   = lane & 15;        // 0-15

    int bid = blockIdx.x;
    bid = (bid & 7) * (512 >> 3) + (bid >> 3);   // XCD swizzle, 512%8==0
    const int bm = bid >> 4;           // 0-31
    const int bn = bid & 15;           // 0-15

    const size_t a_row0 = (size_t)bm * BM;
    const size_t b_row0 = (size_t)bn * BN;

    // A staging: unit = 8KB = 128 logical rows x 64B, 1x16B load/thread,
    // inverse-swizzled source (rule #21), wave-uniform linear LDS dest.
    const int sx  = (tid & 7) ^ ((tid >> 3) & 7);
    const int s_r = ((tid >> 3) << 1) | ((sx >> 2) & 1);   // local row 0..127
    const int s_c = (sx & 3) << 4;                         // col 0..48

    auto stage_half = [&](int buf, int h, int k0) {
        const signed char* src = A + (a_row0 + h * 128 + s_r) * IN_F + k0 + s_c;
        signed char* dst = As + buf * 16384 + h * 8192 + (wave << 10);
        __builtin_amdgcn_global_load_lds((gas_void*)src, (las_void*)dst, 16, 0, 0);
    };
    auto stage_tile = [&](int buf, int k0) { stage_half(buf, 0, k0); stage_half(buf, 1, k0); };

    i32x4 acc[8][4] = {};
    i32x4 a[8], bA[4], bB[4];

    auto physoff = [&](int r, int c0) {
        return ((r >> 1) << 7) + (((((r & 1) << 6) | c0) ^ (((r >> 1) & 7) << 4)));
    };
    int pA[8];
#pragma unroll
    for (int mi = 0; mi < 8; ++mi) pA[mi] = physoff(wm * 128 + mi * 16 + lr, lg << 4);

    // B global per-lane row pointers (loop-invariant; k advances by +t*BK)
    const signed char* bp[4];
#pragma unroll
    for (int ni = 0; ni < 4; ++ni)
        bp[ni] = B + (size_t)(b_row0 + wn * 64 + ni * 16 + lr) * IN_F + lg * 16;

    // ---- prologue: stage A tiles 0,1; load B(0); full drain (once), barrier
    stage_tile(0, 0); stage_tile(1, BK);
#pragma unroll
    for (int ni = 0; ni < 4; ++ni) bA[ni] = *(const i32x4*)(bp[ni] + 0);
    asm volatile("s_waitcnt vmcnt(0)" ::: "memory");
    __builtin_amdgcn_sched_barrier(0);
    __builtin_amdgcn_s_barrier();
    __builtin_amdgcn_sched_barrier(0);

    for (int tt = 0; tt < NT; tt += 2) {
        BODY(tt,     bA, bB);
        BODY(tt + 1, bB, bA);
    }

    // ---- epilogue: out = acc * dx[row] * dw[col]; C/D col=lane&15, row=lg*4+j
    float dwc[4];
#pragma unroll
    for (int ni = 0; ni < 4; ++ni) dwc[ni] = dW[b_row0 + wn * 64 + ni * 16 + lr];

    float* Cp = C + (a_row0 + wm * 128) * (size_t)OUT_F + b_row0 + wn * 64;
#pragma unroll
    for (int mi = 0; mi < 8; ++mi) {
#pragma unroll
        for (int j = 0; j < 4; ++j) {
            const int r = mi * 16 + lg * 4 + j;
            const float dxr = dX[a_row0 + wm * 128 + r];
#pragma unroll
            for (int ni = 0; ni < 4; ++ni)
                Cp[(size_t)r * OUT_F + ni * 16 + lr] =
                    (float)acc[mi][ni][j] * dxr * dwc[ni];
        }
    }
}

extern "C" void kernel_launch(void* const* d_in, const int* in_sizes, int n_in,
                              void* d_out, int out_size, void* d_ws, size_t ws_size,
                              hipStream_t stream) {
    const float* x      = (const float*)d_in[0];
    const int*   tern   = (const int*)d_in[1];
    const float* scales = (const float*)d_in[2];

    signed char* xq = (signed char*)d_ws;
    signed char* wq = xq + (size_t)TOKENS * IN_F;
    float*       dx = (float*)(wq + (size_t)OUT_F * IN_F);
    float*       dw = dx + TOKENS;

    quant_x_kernel<<<TOKENS, 256, 0, stream>>>(x, xq, dx);
    quant_w_kernel<<<OUT_F, 256, 0, stream>>>(tern, scales, wq, dw);

    dim3 grid((TOKENS / BM) * (OUT_F / BN));   // 32*16 = 512
    gemm_i8_kernel<<<grid, 512, 0, stream>>>(xq, wq, dx, dw, (float*)d_out);
}

// Round 10
// 203.530 us; speedup vs baseline: 1.2735x; 1.2735x over previous
//
#include <hip/hip_runtime.h>

#define TOKENS 8192
#define IN_F   4096
#define OUT_F  4096

#define BM 256
#define BN 256
#define BK 64
#define NT (IN_F / BK)   // 64 K-tiles

typedef __attribute__((ext_vector_type(4))) float  f32x4;
typedef __attribute__((ext_vector_type(4))) int    i32x4;

typedef const __attribute__((address_space(1))) void gas_void;
typedef __attribute__((address_space(3))) void las_void;

// ---------------------------------------------------------------------------
// quant_x: per-token symmetric i8 quantization, row-major out (A goes via LDS).
// ---------------------------------------------------------------------------
__global__ __launch_bounds__(256) void quant_x_kernel(const float* __restrict__ x,
                                                      signed char* __restrict__ xq,
                                                      float* __restrict__ dx) {
    const int row  = blockIdx.x;
    const int tid  = threadIdx.x;
    const int lane = tid & 63;
    const int wv   = tid >> 6;
    const float* xr = x + (size_t)row * IN_F;

    float v[16];
#pragma unroll
    for (int k = 0; k < 4; ++k) {
        f32x4 t = *(const f32x4*)(xr + k * 1024 + tid * 4);
#pragma unroll
        for (int j = 0; j < 4; ++j) v[k * 4 + j] = t[j];
    }
    float m = 0.f;
#pragma unroll
    for (int j = 0; j < 16; ++j) m = fmaxf(m, fabsf(v[j]));
#pragma unroll
    for (int off = 32; off >= 1; off >>= 1) m = fmaxf(m, __shfl_xor(m, off));
    __shared__ float sm[4];
    if (lane == 0) sm[wv] = m;
    __syncthreads();
    m = fmaxf(fmaxf(sm[0], sm[1]), fmaxf(sm[2], sm[3]));

    const float inv = 127.0f / m;
    if (tid == 0) dx[row] = m * (1.0f / 127.0f);

    int* out = (int*)(xq + (size_t)row * IN_F);
#pragma unroll
    for (int k = 0; k < 4; ++k) {
        int p = 0;
#pragma unroll
        for (int j = 0; j < 4; ++j) {
            int q = (int)rintf(v[k * 4 + j] * inv);
            p |= (q & 0xff) << (8 * j);
        }
        out[k * 256 + tid] = p;
    }
}

// ---------------------------------------------------------------------------
// quant_w: ternary -> i8 in MFMA FRAGMENT ORDER.
// Granule (bn, kt, g) = 1 KiB at wq[((bn*64+kt)*16+g)*1024 + lane*16]:
//   lane = lg*16+lr holds rows o = bn*256+g*16+lr, k = kt*64+lg*16 .. +16.
// Block = 16 out-rows (one g). 256 thr: lane covers (lr,lg), tid>>6 = kt0,
// loop i: kt = kt0*16+i. Writes: wave-contiguous 1 KiB. Reads: per (row,kt)
// 256B contiguous at line granularity (BW-fine).
// ---------------------------------------------------------------------------
__global__ __launch_bounds__(256) void quant_w_kernel(const int* __restrict__ tern,
                                                      const float* __restrict__ scales,
                                                      signed char* __restrict__ wq,
                                                      float* __restrict__ dw) {
    const int o0   = blockIdx.x << 4;       // first out-row of this granule-row
    const int tid  = threadIdx.x;
    const int lane = tid & 63;
    const int lr   = lane & 15;
    const int lg   = lane >> 4;
    const int kt0  = tid >> 6;              // 0..3

    const int o = o0 + lr;
    const float* sr = scales + o * 32;
    float smax = 0.f;
#pragma unroll
    for (int g = 0; g < 32; ++g) smax = fmaxf(smax, sr[g]);
    const float rs = 127.0f / smax;
    if (tid < 16) dw[o0 + tid] = smax * (1.0f / 127.0f);  // tid<16 has lr==tid

    const int bn  = o0 >> 8;
    const int g16 = (o0 >> 4) & 15;
    signed char* outb = wq + ((size_t)((bn * 64) * 16 + g16) << 10) + lane * 16;

#pragma unroll
    for (int i = 0; i < 16; ++i) {
        const int kt = kt0 * 16 + i;
        const int c  = kt * 4 + lg;          // 16-elem chunk index within row
        const int iq = (int)rintf(sr[c >> 3] * rs);
        const i32x4* tp = (const i32x4*)(tern + (size_t)o * IN_F + c * 16);
        i32x4 w4;
#pragma unroll
        for (int k = 0; k < 4; ++k) {
            i32x4 tt = tp[k];
            int p = 0;
#pragma unroll
            for (int j = 0; j < 4; ++j) p |= ((tt[j] * iq) & 0xff) << (8 * j);
            w4[k] = p;
        }
        *(i32x4*)(outb + ((size_t)(kt * 16) << 10)) = w4;
    }
}

// ---------------------------------------------------------------------------
// C[M][N] = (xq . wq^T) * dx[m] * dw[n],  i8 MFMA 16x16x64, i32 acc.
// 256x256 tile, BK=64, 8 waves (2M x 4N), per-wave 128x64, acc 128 AGPR.
// r10: A via LDS (triple-buffer 48 KiB, r7/r8-verified swizzle);
//      B via DIRECT global->reg, fragment-order wq => coalesced 1 KiB loads,
//      prefetched one K-tile ahead, bA/bB double-buffer (unroll-2, rule #20).
// Body t (single region, r8-style): 8 ds_read a | 4 B-loads(t+1)->regs |
//   stage A(t+2) (2 gload_lds) | 4 QUADs | gate | barrier.
// Gate FIFO audit: issued-in-body-t VMEM (B[4]+stage[2]) is newest;
//   oldest = stageA(t+1)[2] => vmcnt(6) drains it. Tail: vmcnt(4) at NT-2.
//   B-reg uses are compiler-tracked (auto vmcnt before QUAD use).
// ---------------------------------------------------------------------------

#define QUAD(MI0, NI0, BC)                                                     \
  do {                                                                         \
    __builtin_amdgcn_s_setprio(1);                                             \
    _Pragma("unroll") for (int mi = 0; mi < 4; ++mi)                           \
      _Pragma("unroll") for (int ni = 0; ni < 2; ++ni)                         \
          acc[(MI0)+mi][(NI0)+ni] = __builtin_amdgcn_mfma_i32_16x16x64_i8(     \
              a[(MI0)+mi], BC[(NI0)+ni], acc[(MI0)+mi][(NI0)+ni], 0, 0, 0);    \
    __builtin_amdgcn_s_setprio(0);                                             \
  } while (0)

#define BODY(T, BC, BNX)                                                       \
  do {                                                                         \
    const int abase_ = ((T) % 3) * 16384;                                      \
    _Pragma("unroll") for (int mi = 0; mi < 8; ++mi)                           \
        a[mi] = *(const i32x4*)&As[abase_ + pA[mi]];                           \
    if ((T) + 1 < NT) {                                                        \
      _Pragma("unroll") for (int ni = 0; ni < 4; ++ni)                         \
          BNX[ni] = *(const i32x4*)(bF + ni * 1024 + ((T) + 1) * 16384);       \
    }                                                                          \
    if ((T) + 2 < NT) stage_tile(((T) + 2) % 3, ((T) + 2) * BK);               \
    QUAD(0, 0, BC); QUAD(0, 2, BC); QUAD(4, 0, BC); QUAD(4, 2, BC);            \
    if ((T) + 2 < NT)      asm volatile("s_waitcnt vmcnt(6)" ::: "memory");    \
    else if ((T) + 1 < NT) asm volatile("s_waitcnt vmcnt(4)" ::: "memory");    \
    __builtin_amdgcn_sched_barrier(0);                                         \
    __builtin_amdgcn_s_barrier();                                              \
    __builtin_amdgcn_sched_barrier(0);                                         \
  } while (0)

__global__ __launch_bounds__(512, 2) void gemm_i8_kernel(
        const signed char* __restrict__ A,
        const signed char* __restrict__ B,
        const float* __restrict__ dX,
        const float* __restrict__ dW,
        float* __restrict__ C) {
    __shared__ __align__(16) signed char As[3 * 16384];

    const int tid  = threadIdx.x;
    const int wave = tid >> 6;
    const int lane = tid & 63;
    const int wm   = wave >> 2;        // 0-1
    const int wn   = wave & 3;         // 0-3
    const int lg   = lane >> 4;        // 0-3
    const int lr   = lane & 15;        // 0-15

    int bid = blockIdx.x;
    bid = (bid & 7) * (512 >> 3) + (bid >> 3);   // XCD swizzle, 512%8==0
    const int bm = bid >> 4;           // 0-31
    const int bn = bid & 15;           // 0-15

    const size_t a_row0 = (size_t)bm * BM;
    const size_t b_row0 = (size_t)bn * BN;

    // A staging: unit = 8KB = 128 rows x 64B, 1x16B load/thread,
    // inverse-swizzled source (rule #21), wave-uniform linear LDS dest.
    const int sx  = (tid & 7) ^ ((tid >> 3) & 7);
    const int s_r = ((tid >> 3) << 1) | ((sx >> 2) & 1);
    const int s_c = (sx & 3) << 4;

    auto stage_half = [&](int buf, int h, int k0) {
        const signed char* src = A + (a_row0 + h * 128 + s_r) * IN_F + k0 + s_c;
        signed char* dst = As + buf * 16384 + h * 8192 + (wave << 10);
        __builtin_amdgcn_global_load_lds((gas_void*)src, (las_void*)dst, 16, 0, 0);
    };
    auto stage_tile = [&](int buf, int k0) { stage_half(buf, 0, k0); stage_half(buf, 1, k0); };

    i32x4 acc[8][4] = {};
    i32x4 a[8], bA[4], bB[4];

    auto physoff = [&](int r, int c0) {
        return ((r >> 1) << 7) + (((((r & 1) << 6) | c0) ^ (((r >> 1) & 7) << 4)));
    };
    int pA[8];
#pragma unroll
    for (int mi = 0; mi < 8; ++mi) pA[mi] = physoff(wm * 128 + mi * 16 + lr, lg << 4);

    // B fragment base: granule (bn, kt=0, g = wn*4 + ni), this lane's 16B.
    const signed char* bF = B + ((size_t)(bn * 64 * 16 + wn * 4) << 10) + lane * 16;

    // ---- prologue: stage A tiles 0,1; load B(0); vmcnt(6) drains stage(0)
    stage_tile(0, 0); stage_tile(1, BK);
#pragma unroll
    for (int ni = 0; ni < 4; ++ni) bA[ni] = *(const i32x4*)(bF + ni * 1024);
    asm volatile("s_waitcnt vmcnt(6)" ::: "memory");
    __builtin_amdgcn_sched_barrier(0);
    __builtin_amdgcn_s_barrier();
    __builtin_amdgcn_sched_barrier(0);

    for (int tt = 0; tt < NT; tt += 2) {
        BODY(tt,     bA, bB);
        BODY(tt + 1, bB, bA);
    }

    // ---- epilogue: out = acc * dx[row] * dw[col]; C/D col=lane&15, row=lg*4+j
    float dwc[4];
#pragma unroll
    for (int ni = 0; ni < 4; ++ni) dwc[ni] = dW[b_row0 + wn * 64 + ni * 16 + lr];

    float* Cp = C + (a_row0 + wm * 128) * (size_t)OUT_F + b_row0 + wn * 64;
#pragma unroll
    for (int mi = 0; mi < 8; ++mi) {
#pragma unroll
        for (int j = 0; j < 4; ++j) {
            const int r = mi * 16 + lg * 4 + j;
            const float dxr = dX[a_row0 + wm * 128 + r];
#pragma unroll
            for (int ni = 0; ni < 4; ++ni)
                Cp[(size_t)r * OUT_F + ni * 16 + lr] =
                    (float)acc[mi][ni][j] * dxr * dwc[ni];
        }
    }
}

extern "C" void kernel_launch(void* const* d_in, const int* in_sizes, int n_in,
                              void* d_out, int out_size, void* d_ws, size_t ws_size,
                              hipStream_t stream) {
    const float* x      = (const float*)d_in[0];
    const int*   tern   = (const int*)d_in[1];
    const float* scales = (const float*)d_in[2];

    signed char* xq = (signed char*)d_ws;
    signed char* wq = xq + (size_t)TOKENS * IN_F;
    float*       dx = (float*)(wq + (size_t)OUT_F * IN_F);
    float*       dw = dx + TOKENS;

    quant_x_kernel<<<TOKENS, 256, 0, stream>>>(x, xq, dx);
    quant_w_kernel<<<OUT_F / 16, 256, 0, stream>>>(tern, scales, wq, dw);

    dim3 grid((TOKENS / BM) * (OUT_F / BN));   // 32*16 = 512
    gemm_i8_kernel<<<grid, 512, 0, stream>>>(xq, wq, dx, dw, (float*)d_out);
}